// Round 10
// baseline (253.280 us; speedup 1.0000x reference)
//
#include <hip/hip_runtime.h>

// AttentionBlock: B=8, S=2048, D=512, fp32 in/out, bf16 MFMA internally.
// R17 = R15 flash (verified ~75.5 us) + CONTIGUOUS reg-direct proj:
//   prep now emits xb and WT in packed 32x32-fragment chunk layouts, so proj's
//   barrier-free mainloop loads A/B as CONTIGUOUS 1KB wave-loads (R9's reg-direct
//   idea minus its TA-scatter wall). 1 A + 6 B chunks + 6 mfma_32x32x16 per BK=16
//   step, acc[3][2] f32x16 = 96 regs, zero barriers, zero LDS in mainloop.
// Packed chunk layouts (lane = non-K dim, 8 K-elems per lane, 1KB per chunk):
//   xbp/Q32/K32 chunk(g,kst): row = g*32+(l&31), d = kst*16+(l>>5)*8+j, idx = g*32+kst
//   WTP         chunk(gc,kst): col = gc*32+(l&31), k = kst*16+(l>>5)*8+j, idx(z) = gc*32+kst
//   V32         chunk(ng,kv):  dim = ng*32+(l&31), key = kv*16+(l>>5)*8+j, idx = ng*128+kv
// ws: WTP bf16[3][512][512] | QP 16MB | KP 16MB | VP 16MB | xbp 16MB

typedef __attribute__((ext_vector_type(8))) short bf16x8;
typedef __attribute__((ext_vector_type(4))) short short4v;
typedef __attribute__((ext_vector_type(4))) float f32x4;
typedef __attribute__((ext_vector_type(16))) float f32x16;

__device__ __forceinline__ short f2bf(float f) {
  union { float f; unsigned u; } v; v.f = f;
  unsigned r = v.u + 0x7fffu + ((v.u >> 16) & 1u);
  return (short)(r >> 16);
}

__device__ __forceinline__ float exp2_raw(float x) {
  float r;
  asm("v_exp_f32 %0, %1" : "=v"(r) : "v"(x));
  return r;
}

// ---------------- kernel 0: prep -> packed-fragment xbp and WTP ----------------
__global__ __launch_bounds__(256) void prep_kernel(const float* __restrict__ x,
                                                   const float* __restrict__ Wq,
                                                   const float* __restrict__ Wk,
                                                   const float* __restrict__ Wv,
                                                   short* __restrict__ WTP,
                                                   short* __restrict__ xbp) {
  if (blockIdx.x < 384) {
    // W -> WTP packed B-chunks: chunk c = gc*32+kst, lane ln2: col = gc*32+(ln2&31),
    // k = kst*16+(ln2>>5)*8+j. Write coalesced (1KB/wave), read col-strided (as before).
    int g = blockIdx.x * 256 + threadIdx.x;  // 3 * 512 chunks * 64 lanes
    int z = g >> 15;
    int rem = g & 32767;
    int c = rem >> 6, ln2 = rem & 63;
    int gc = c >> 5, kst = c & 31;
    const float* W = (z == 0) ? Wq : ((z == 1) ? Wk : Wv);
    const int col = gc * 32 + (ln2 & 31);
    const int k0 = kst * 16 + ((ln2 >> 5) << 3);
    bf16x8 o;
#pragma unroll
    for (int j = 0; j < 8; ++j) o[j] = f2bf(W[(k0 + j) * 512 + col]);
    *(bf16x8*)(WTP + z * 262144 + c * 512 + ln2 * 8) = o;
  } else {
    // x -> xbp packed A-chunks. Wave = one source row (fully coalesced 2KB read);
    // writes are 16B granules within the row's 32KB g-block.
    int t = (blockIdx.x - 384) * 256 + threadIdx.x;  // 1,048,576 threads
    const int r = t >> 6;             // source row
    const int d0 = (t & 63) * 8;      // d-octet
    f32x4 lo = *(const f32x4*)(x + (size_t)r * 512 + d0);
    f32x4 hi = *(const f32x4*)(x + (size_t)r * 512 + d0 + 4);
    bf16x8 o;
    o[0] = f2bf(lo[0]); o[1] = f2bf(lo[1]); o[2] = f2bf(lo[2]); o[3] = f2bf(lo[3]);
    o[4] = f2bf(hi[0]); o[5] = f2bf(hi[1]); o[6] = f2bf(hi[2]); o[7] = f2bf(hi[3]);
    const int gg = r >> 5, l31 = r & 31;
    const int kst = d0 >> 4, hq2 = (d0 >> 3) & 1;
    *(bf16x8*)(xbp + (size_t)(gg * 32 + kst) * 512 + (hq2 * 32 + l31) * 8) = o;
  }
}

// ---------------- kernel 1: proj GEMM — barrier-free, LDS-free, contiguous loads ----------------
// grid (128, 8): m0 = bx*128 rows, n0 = by*64 cols, z-fused. 4 waves; wave wv owns
// m-group (m0>>5)+wv (32 rows) x both 32-col n-groups x 3 z. 32 K-steps of BK=16.
__global__ __launch_bounds__(256, 2) void proj_kernel(const short* __restrict__ xbp,
                                                      const short* __restrict__ WTP,
                                                      short* __restrict__ QP,
                                                      short* __restrict__ KP,
                                                      short* __restrict__ VP) {
  __shared__ __align__(16) short Tb[8704];  // epilogue transpose buffer only

  const int tid = threadIdx.x, wv = tid >> 6, ln = tid & 63;
  const int q32 = ln & 31, hq = ln >> 5;
  const int m0 = blockIdx.x * 128, n0 = blockIdx.y * 64;

  const short* apt = xbp + (size_t)(((m0 >> 5) + wv) * 32) * 512 + ln * 8;
  const short* bpt[3][2];
#pragma unroll
  for (int z = 0; z < 3; ++z)
#pragma unroll
    for (int nj = 0; nj < 2; ++nj)
      bpt[z][nj] = WTP + z * 262144 + (size_t)(((n0 >> 5) + nj) * 32) * 512 + ln * 8;

  f32x16 zz = {};
  f32x16 acc[3][2];
#pragma unroll
  for (int z = 0; z < 3; ++z) { acc[z][0] = zz; acc[z][1] = zz; }

#pragma unroll
  for (int kst = 0; kst < 32; ++kst) {
    bf16x8 a = *(const bf16x8*)(apt + kst * 512);
    bf16x8 b00 = *(const bf16x8*)(bpt[0][0] + kst * 512);
    bf16x8 b01 = *(const bf16x8*)(bpt[0][1] + kst * 512);
    bf16x8 b10 = *(const bf16x8*)(bpt[1][0] + kst * 512);
    bf16x8 b11 = *(const bf16x8*)(bpt[1][1] + kst * 512);
    bf16x8 b20 = *(const bf16x8*)(bpt[2][0] + kst * 512);
    bf16x8 b21 = *(const bf16x8*)(bpt[2][1] + kst * 512);
    acc[0][0] = __builtin_amdgcn_mfma_f32_32x32x16_bf16(a, b00, acc[0][0], 0, 0, 0);
    acc[0][1] = __builtin_amdgcn_mfma_f32_32x32x16_bf16(a, b01, acc[0][1], 0, 0, 0);
    acc[1][0] = __builtin_amdgcn_mfma_f32_32x32x16_bf16(a, b10, acc[1][0], 0, 0, 0);
    acc[1][1] = __builtin_amdgcn_mfma_f32_32x32x16_bf16(a, b11, acc[1][1], 0, 0, 0);
    acc[2][0] = __builtin_amdgcn_mfma_f32_32x32x16_bf16(a, b20, acc[2][0], 0, 0, 0);
    acc[2][1] = __builtin_amdgcn_mfma_f32_32x32x16_bf16(a, b21, acc[2][1], 0, 0, 0);
  }

  // D layout (verified R7): col = lane&31 (n), row = (reg&3)+8*(reg>>2)+4*hq (m-local).
  // ---- Q,K epilogues: Tb row-major [128][68]; packed chunks (gl 0..3) x (kl 0..3) ----
#pragma unroll
  for (int z = 0; z < 2; ++z) {
    __syncthreads();
#pragma unroll
    for (int nj = 0; nj < 2; ++nj)
#pragma unroll
      for (int reg = 0; reg < 16; ++reg) {
        const int mloc = wv * 32 + (reg & 3) + 8 * (reg >> 2) + 4 * hq;
        Tb[mloc * 68 + nj * 32 + q32] = f2bf(acc[z][nj][reg]);
      }
    __syncthreads();
    short* Odst = (z == 0) ? QP : KP;
    const int kst0 = n0 >> 4;
#pragma unroll
    for (int p = 0; p < 4; ++p) {
      const int c2 = p * 256 + tid;
      const int frag = c2 >> 6, ln2 = c2 & 63;
      const int gl = frag >> 2, kl = frag & 3;
      const short* src = Tb + (gl * 32 + (ln2 & 31)) * 68 + kl * 16 + ((ln2 >> 5) << 3);
      size_t dst = ((size_t)((m0 >> 5) + gl) * 32 + kst0 + kl) * 512 + ln2 * 8;
      *(bf16x8*)(Odst + dst) = *(const bf16x8*)src;
    }
  }
  // ---- V epilogue: Tb d-major [64][132]; packed chunks (ngl 0..1) x (kvl 0..7) ----
  {
    __syncthreads();
#pragma unroll
    for (int nj = 0; nj < 2; ++nj)
#pragma unroll
      for (int reg = 0; reg < 16; ++reg) {
        const int mloc = wv * 32 + (reg & 3) + 8 * (reg >> 2) + 4 * hq;
        Tb[(nj * 32 + q32) * 132 + mloc] = f2bf(acc[2][nj][reg]);
      }
    __syncthreads();
    const int ng0 = n0 >> 5, kv0 = (m0 & 2047) >> 4;
    const size_t vbase = (size_t)(m0 >> 11) * 1048576;
#pragma unroll
    for (int p = 0; p < 4; ++p) {
      const int c2 = p * 256 + tid;
      const int frag = c2 >> 6, ln2 = c2 & 63;
      const int ngl = frag >> 3, kvl = frag & 7;
      const short* src = Tb + (ngl * 32 + (ln2 & 31)) * 132 + kvl * 16 + ((ln2 >> 5) << 3);
      size_t dst = vbase + (size_t)((ng0 + ngl) * 128 + kv0 + kvl) * 512 + ln2 * 8;
      *(bf16x8*)(VP + dst) = *(const bf16x8*)src;
    }
  }
}

// ---------------- kernel 2: flash attention, S^T/O^T 32x32, KVBLK=256, fixed roles ----------------
// (verified R15: ~75.5 us, VGPR 112, FETCH 24.6 MB, no spill) — byte-identical.

#define ISSUE8(R, a0_, a1_, B)                                               \
  asm volatile("global_load_dwordx4 %0, %8, %10\n\t"                         \
               "global_load_dwordx4 %1, %8, %10 offset:1024\n\t"             \
               "global_load_dwordx4 %2, %8, %10 offset:2048\n\t"             \
               "global_load_dwordx4 %3, %8, %10 offset:3072\n\t"             \
               "global_load_dwordx4 %4, %9, %10\n\t"                         \
               "global_load_dwordx4 %5, %9, %10 offset:1024\n\t"             \
               "global_load_dwordx4 %6, %9, %10 offset:2048\n\t"             \
               "global_load_dwordx4 %7, %9, %10 offset:3072\n\t"             \
               : "=&v"(R[0]), "=&v"(R[1]), "=&v"(R[2]), "=&v"(R[3]),         \
                 "=&v"(R[4]), "=&v"(R[5]), "=&v"(R[6]), "=&v"(R[7])          \
               : "v"(a0_), "v"(a1_), "s"(B))

#define WAIT8(R, N)                                                          \
  asm volatile("s_waitcnt vmcnt(" #N ")"                                     \
               : "+v"(R[0]), "+v"(R[1]), "+v"(R[2]), "+v"(R[3]),             \
                 "+v"(R[4]), "+v"(R[5]), "+v"(R[6]), "+v"(R[7]))

#define MFMA32(A, B, C) __builtin_amdgcn_mfma_f32_32x32x16_bf16(A, B, C, 0, 0, 0)

#define ISSUE_KQ(X, kt_, qq)                                                 \
  { const unsigned a0 = kb0 + (unsigned)(((kt_) & 7) * 262144) + (qq) * 8192u; \
    ISSUE8(X, a0, a0 + 4096u, Kp); }

#define ISSUE_VQ(X, kt_, bb_)                                                \
  { const unsigned a0 = vb0 + (unsigned)((kt_) * 16384) + (bb_) * 4096u;     \
    ISSUE8(X, a0, a0 + 131072u, VTp); }

#define S_PHASE(X, ph)                                                       \
  WAIT8(X, 8);                                                               \
  __builtin_amdgcn_s_setprio(1);                                             \
  _Pragma("unroll")                                                          \
  for (int c = 0; c < 8; ++c) {                                              \
    const int kst = (ph) * 8 + c;                                            \
    bf16x8 q0 = *(bf16x8*)(qf + kst * 512 + ln * 8);                         \
    bf16x8 q1 = *(bf16x8*)(qf + (32 + kst) * 512 + ln * 8);                  \
    s0 = MFMA32(X[c], q0, s0);                                               \
    s1 = MFMA32(X[c], q1, s1);                                               \
  }                                                                          \
  __builtin_amdgcn_s_setprio(0);

#define PF_RD(qh_, kv_)                                                      \
  (*(bf16x8*)(pfb + (qh_) * 8192 + q32 * 256 + ((((kv_) * 16) + hq8) ^ sw3)))

#define PV_PHASE(X, bb_)                                                     \
  WAIT8(X, 8);                                                               \
  __builtin_amdgcn_s_setprio(1);                                             \
  _Pragma("unroll")                                                          \
  for (int c = 0; c < 4; ++c) {                                              \
    const int kv = (bb_) * 4 + c;                                            \
    bf16x8 p0 = PF_RD(0, kv);                                                \
    bf16x8 p1 = PF_RD(1, kv);                                                \
    O00 = MFMA32(X[c], p0, O00);                                             \
    O01 = MFMA32(X[c], p1, O01);                                             \
    O10 = MFMA32(X[4 + c], p0, O10);                                         \
    O11 = MFMA32(X[4 + c], p1, O11);                                         \
  }                                                                          \
  __builtin_amdgcn_s_setprio(0);

__global__ __launch_bounds__(512, 2) void flash_kernel(const short* __restrict__ Q,
                                                       const short* __restrict__ K,
                                                       const short* __restrict__ VT,
                                                       float* __restrict__ out) {
  __shared__ __align__(16) short qf[32768];  // Q chunks [qb2][kst32] = 64 KB
  __shared__ __align__(16) short pf[32768];  // P^T [qh2][q32][k256], dbuf 2 x 32 KB
  __shared__ float l_red[8][64];
  __shared__ float lsum[64];

  const int tid = threadIdx.x, w = tid >> 6, ln = tid & 63;
  const int q32 = ln & 31, hq = ln >> 5;
  const int hq8 = hq * 8, hq4 = hq * 4;
  const int sw3 = (q32 & 7) << 3;
  const int b = blockIdx.x & 7, qt = blockIdx.x >> 3;
  const int m0 = qt * 64;
  const short* Qp = Q + (size_t)b * 1048576;
  const short* Kp = K + (size_t)b * 1048576;
  const short* VTp = VT + (size_t)b * 1048576;
  const float sc2 = 0.044194173824159216f * 1.4426950408889634f;  // 1/sqrt(512)*log2(e)

  // stage Q (64 chunks, straight copy; region = qb*32 + kst = chunk - qt*64)
#pragma unroll
  for (int r = 0; r < 8; ++r) {
    const int reg = w * 8 + r;
    *(bf16x8*)(qf + reg * 512 + ln * 8) =
        *(const bf16x8*)(Qp + (size_t)(qt * 64 + reg) * 512 + ln * 8);
  }

  f32x16 zz = {};
  f32x16 O00 = zz, O01 = zz, O10 = zz, O11 = zz;
  float lp0 = 0.f, lp1 = 0.f;

  const unsigned kb0 = (unsigned)(w * 32768 + ln * 16);
  const unsigned vb0 = (unsigned)(w * 262144 + ln * 16);

  __syncthreads();  // qf ready; vmcnt clean

  bf16x8 kX[8], kY[8], vA[8], vB[8];
  ISSUE_KQ(kX, 0, 0);
  ISSUE_KQ(kY, 0, 1);  // out = 16

#pragma unroll 1
  for (int kt = 0; kt < 8; ++kt) {
    f32x16 s0 = zz, s1 = zz;
    short* pfb = pf + (kt & 1) * 16384;

    S_PHASE(kX, 0); ISSUE_KQ(kX, kt, 2);
    S_PHASE(kY, 1); ISSUE_KQ(kY, kt, 3);
    S_PHASE(kX, 2); ISSUE_VQ(vA, kt, 0);
    S_PHASE(kY, 3); ISSUE_VQ(vB, kt, 1);

    // ---- inline softmax: p = 2^(s*sc2 - 12); write P^T b64 groups (swizzled); accumulate l ----
#pragma unroll
    for (int g2 = 0; g2 < 4; ++g2) {
      float a0 = exp2_raw(s0[g2 * 4 + 0] * sc2 - 12.0f);
      float a1 = exp2_raw(s0[g2 * 4 + 1] * sc2 - 12.0f);
      float a2 = exp2_raw(s0[g2 * 4 + 2] * sc2 - 12.0f);
      float a3 = exp2_raw(s0[g2 * 4 + 3] * sc2 - 12.0f);
      lp0 += (a0 + a1) + (a2 + a3);
      short4v v0c = {f2bf(a0), f2bf(a1), f2bf(a2), f2bf(a3)};
      *(short4v*)(pfb + q32 * 256 + (((w * 32 + g2 * 8) + hq4) ^ sw3)) = v0c;
      float c0 = exp2_raw(s1[g2 * 4 + 0] * sc2 - 12.0f);
      float c1 = exp2_raw(s1[g2 * 4 + 1] * sc2 - 12.0f);
      float c2 = exp2_raw(s1[g2 * 4 + 2] * sc2 - 12.0f);
      float c3 = exp2_raw(s1[g2 * 4 + 3] * sc2 - 12.0f);
      lp1 += (c0 + c1) + (c2 + c3);
      short4v v1c = {f2bf(c0), f2bf(c1), f2bf(c2), f2bf(c3)};
      *(short4v*)(pfb + 8192 + q32 * 256 + (((w * 32 + g2 * 8) + hq4) ^ sw3)) = v1c;
    }
    // RAW barrier: drain LDS only; V0,V1 (16 loads) stay in flight across it
    asm volatile("s_waitcnt lgkmcnt(0)" ::: "memory");
    __builtin_amdgcn_s_barrier();
    asm volatile("" ::: "memory");

    PV_PHASE(vA, 0); ISSUE_VQ(vA, kt, 2);
    PV_PHASE(vB, 1); ISSUE_VQ(vB, kt, 3);
    PV_PHASE(vA, 2); ISSUE_KQ(kX, kt + 1, 0);
    PV_PHASE(vB, 3); ISSUE_KQ(kY, kt + 1, 1);
  }
  // drain dangling wrapped-tile prefetches (register-tied)
  WAIT8(kX, 8);
  WAIT8(kY, 0);

  // ---- l: fold hq halves, publish per-wave partials, sum 8 waves ----
  lp0 += __shfl_xor(lp0, 32);
  lp1 += __shfl_xor(lp1, 32);
  if (ln < 32) {
    l_red[w][q32] = lp0;
    l_red[w][32 + q32] = lp1;
  }
  __syncthreads();
  if (tid < 64) {
    float s = 0.f;
#pragma unroll
    for (int ww = 0; ww < 8; ++ww) s += l_red[ww][tid];
    lsum[tid] = s;
  }
  __syncthreads();

  // ---- epilogue: O^T regs -> out[q][d], f32x4 packed stores (d-quads) ----
  const float li0 = 1.f / lsum[q32];
  const float li1 = 1.f / lsum[32 + q32];
#pragma unroll
  for (int g2 = 0; g2 < 4; ++g2) {
    const int dq = g2 * 8 + hq4;  // d-local base within ng: crow = i + 8*g2 + 4*hq
    const size_t r0 = ((size_t)b * 2048 + m0 + q32) * 512 + w * 64;
    const size_t r1 = ((size_t)b * 2048 + m0 + 32 + q32) * 512 + w * 64;
    f32x4 o;
    o[0] = O00[g2 * 4 + 0] * li0; o[1] = O00[g2 * 4 + 1] * li0;
    o[2] = O00[g2 * 4 + 2] * li0; o[3] = O00[g2 * 4 + 3] * li0;
    *(f32x4*)(out + r0 + dq) = o;
    o[0] = O10[g2 * 4 + 0] * li0; o[1] = O10[g2 * 4 + 1] * li0;
    o[2] = O10[g2 * 4 + 2] * li0; o[3] = O10[g2 * 4 + 3] * li0;
    *(f32x4*)(out + r0 + 32 + dq) = o;
    o[0] = O01[g2 * 4 + 0] * li1; o[1] = O01[g2 * 4 + 1] * li1;
    o[2] = O01[g2 * 4 + 2] * li1; o[3] = O01[g2 * 4 + 3] * li1;
    *(f32x4*)(out + r1 + dq) = o;
    o[0] = O11[g2 * 4 + 0] * li1; o[1] = O11[g2 * 4 + 1] * li1;
    o[2] = O11[g2 * 4 + 2] * li1; o[3] = O11[g2 * 4 + 3] * li1;
    *(f32x4*)(out + r1 + 32 + dq) = o;
  }
}

extern "C" void kernel_launch(void* const* d_in, const int* in_sizes, int n_in,
                              void* d_out, int out_size, void* d_ws, size_t ws_size,
                              hipStream_t stream) {
  const float* x  = (const float*)d_in[0];
  const float* Wq = (const float*)d_in[1];
  const float* Wk = (const float*)d_in[2];
  const float* Wv = (const float*)d_in[3];
  float* out = (float*)d_out;
  char* ws = (char*)d_ws;
  short* WTP = (short*)ws;
  short* QP = (short*)(ws + 1572864);
  short* KP = (short*)(ws + 1572864 + 16777216);
  short* VP = (short*)(ws + 1572864 + 2 * 16777216);
  short* xbp = (short*)(ws + 1572864 + 3 * 16777216);

  prep_kernel<<<dim3(384 + 4096), dim3(256), 0, stream>>>(x, Wq, Wk, Wv, WTP, xbp);
  proj_kernel<<<dim3(128, 8), dim3(256), 0, stream>>>(xbp, WTP, QP, KP, VP);
  flash_kernel<<<dim3(256), dim3(512), 0, stream>>>(QP, KP, VP, out);
}

// Round 11
// 203.548 us; speedup vs baseline: 1.2443x; 1.2443x over previous
//
#include <hip/hip_runtime.h>

// AttentionBlock: B=8, S=2048, D=512, fp32 in/out, bf16 MFMA internally.
// R18 = R8 config (total 210, flash 75.6 verified) with proj sync REBUILT:
//   double-buffered async_cp16 staging + counted vmcnt(5) + raw barrier pair per step.
//   R8's __syncthreads-after-stage forced vmcnt(0) drains (serial stage<->compute);
//   now stage k+1 rides across barrier+compute k (T3/T4). Compute/epilogues unchanged.
//   (R9/R10 lesson: reg-direct proj has no operand-sharing network -> 10% MfmaUtil;
//    LDS staging IS the distribution network. Keep it; fix only the drains.)
// flash: S^T/O^T 32x32, 4 fixed-role 8-frag asm arrays, 1 barrier/iter, vmcnt(8),
//   setprio around MFMA, raw v_exp_f32 softmax. (R15, byte-identical.)
// Packed 32x32 chunk layouts (1KB contiguous wave-loads), produced by proj epilogue:
//   Q32/K32 chunk(g,kst): row = g*32+(l&31), d = kst*16+(l>>5)*8+j, idx = g*32+kst
//   V32     chunk(ng,kv): dim = ng*32+(l&31), key = kv*16+(l>>5)*8+j, idx = ng*128+kv
// ws: WT bf16[3][512][512] | QP 16MB | KP 16MB | VP 16MB | xb 16MB

typedef __attribute__((ext_vector_type(8))) short bf16x8;
typedef __attribute__((ext_vector_type(4))) short short4v;
typedef __attribute__((ext_vector_type(4))) float f32x4;
typedef __attribute__((ext_vector_type(16))) float f32x16;

__device__ __forceinline__ short f2bf(float f) {
  union { float f; unsigned u; } v; v.f = f;
  unsigned r = v.u + 0x7fffu + ((v.u >> 16) & 1u);
  return (short)(r >> 16);
}

__device__ __forceinline__ float exp2_raw(float x) {
  float r;
  asm("v_exp_f32 %0, %1" : "=v"(r) : "v"(x));
  return r;
}

__device__ __forceinline__ void async_cp16(const void* g, void* l) {
  __builtin_amdgcn_global_load_lds(
      (const __attribute__((address_space(1))) unsigned int*)g,
      (__attribute__((address_space(3))) unsigned int*)l, 16, 0, 0);
}

// ---------------- kernel 0: prep = W transpose+cvt  AND  x -> bf16 ----------------
__global__ __launch_bounds__(256) void prep_kernel(const float* __restrict__ x,
                                                   const float* __restrict__ Wq,
                                                   const float* __restrict__ Wk,
                                                   const float* __restrict__ Wv,
                                                   short* __restrict__ WT,
                                                   short* __restrict__ xb) {
  if (blockIdx.x < 384) {
    int g = blockIdx.x * 256 + threadIdx.x;  // 3*512*64
    int w = g >> 15;
    int rem = g & 32767;
    int n = rem & 511;
    int k0 = (rem >> 9) << 3;
    const float* W = (w == 0) ? Wq : ((w == 1) ? Wk : Wv);
    bf16x8 o;
#pragma unroll
    for (int j = 0; j < 8; ++j) o[j] = f2bf(W[(k0 + j) * 512 + n]);
    *(bf16x8*)(WT + w * 262144 + n * 512 + k0) = o;
  } else {
    size_t g = (size_t)(blockIdx.x - 384) * 256 + threadIdx.x;
    size_t off = g * 8;
    f32x4 lo = *(const f32x4*)(x + off);
    f32x4 hi = *(const f32x4*)(x + off + 4);
    bf16x8 o;
    o[0] = f2bf(lo[0]); o[1] = f2bf(lo[1]); o[2] = f2bf(lo[2]); o[3] = f2bf(lo[3]);
    o[4] = f2bf(hi[0]); o[5] = f2bf(hi[1]); o[6] = f2bf(hi[2]); o[7] = f2bf(hi[3]);
    *(bf16x8*)(xb + off) = o;
  }
}

// ---------------- kernel 1: Z-FUSED proj GEMM, dbuf staging, counted vmcnt ----------------
// grid (128, 8): m0 = bx*128, n0 = by*64. 4 waves 2x2 (wm,wn). Per BK=32 step:
//   [stage k+1 (5 async_cp16/wave) into buf^1] [vmcnt(5): stage k landed] [barrier]
//   [10 ds_read + 24 MFMA from buf^0] [barrier].  Stage loads ride across barriers.
__global__ __launch_bounds__(256, 3) void proj_kernel(const short* __restrict__ xb,
                                                      const short* __restrict__ WT,
                                                      short* __restrict__ QP,
                                                      short* __restrict__ KP,
                                                      short* __restrict__ VP) {
  __shared__ __align__(16) short smem[20480];  // dbuf 2 x (Af 4096 + Bf 6144); Tb aliases
  short* Tb = smem;

  const int tid = threadIdx.x, wv = tid >> 6, ln = tid & 63;
  const int lane_m = ln & 15, lane_q = ln >> 4;
  const int m0 = blockIdx.x * 128, n0 = blockIdx.y * 64;
  const int wm = wv & 1, wn = wv >> 1;

  f32x4 zero4 = {0.f, 0.f, 0.f, 0.f};
  f32x4 acc[3][4][2];
#pragma unroll
  for (int z = 0; z < 3; ++z)
#pragma unroll
    for (int i = 0; i < 4; ++i)
#pragma unroll
      for (int j = 0; j < 2; ++j) acc[z][i][j] = zero4;

#define PROJ_STAGE(kk_, buf_)                                                          \
  {                                                                                    \
    const int k0s = (kk_) * 32;                                                        \
    short* Afs = smem + (buf_) * 10240;                                                \
    short* Bfs = Afs + 4096;                                                           \
    _Pragma("unroll")                                                                  \
    for (int i = 0; i < 2; ++i) {                                                      \
      const int mt = wv * 2 + i;                                                       \
      async_cp16(xb + (size_t)(m0 + mt * 16 + lane_m) * 512 + k0s + lane_q * 8,        \
                 Afs + mt * 512);                                                      \
    }                                                                                  \
    _Pragma("unroll")                                                                  \
    for (int z = 0; z < 3; ++z)                                                        \
      async_cp16(WT + z * 262144 + (size_t)(n0 + wv * 16 + lane_m) * 512 + k0s +       \
                     lane_q * 8,                                                       \
                 Bfs + z * 2048 + wv * 512);                                           \
  }

  PROJ_STAGE(0, 0);  // 5 loads in flight

#pragma unroll 1
  for (int kk = 0; kk < 16; ++kk) {
    if (kk < 15) {
      PROJ_STAGE(kk + 1, (kk + 1) & 1);  // outstanding = 10
      asm volatile("s_waitcnt vmcnt(5) lgkmcnt(0)" ::: "memory");  // stage kk landed
    } else {
      asm volatile("s_waitcnt vmcnt(0) lgkmcnt(0)" ::: "memory");
    }
    __builtin_amdgcn_s_barrier();
    asm volatile("" ::: "memory");

    short* Af = smem + (kk & 1) * 10240;
    short* Bf = Af + 4096;
    bf16x8 a[4];
#pragma unroll
    for (int mi = 0; mi < 4; ++mi) a[mi] = *(bf16x8*)(Af + ((wm * 4 + mi) * 64 + ln) * 8);
#pragma unroll
    for (int z = 0; z < 3; ++z) {
      bf16x8 b0 = *(bf16x8*)(Bf + z * 2048 + (wn * 2 + 0) * 512 + ln * 8);
      bf16x8 b1 = *(bf16x8*)(Bf + z * 2048 + (wn * 2 + 1) * 512 + ln * 8);
#pragma unroll
      for (int mi = 0; mi < 4; ++mi) {
        acc[z][mi][0] = __builtin_amdgcn_mfma_f32_16x16x32_bf16(a[mi], b0, acc[z][mi][0], 0, 0, 0);
        acc[z][mi][1] = __builtin_amdgcn_mfma_f32_16x16x32_bf16(a[mi], b1, acc[z][mi][1], 0, 0, 0);
      }
    }
    asm volatile("" ::: "memory");
    __builtin_amdgcn_s_barrier();  // all waves done reading buf kk&1 before its reuse
  }

  const int bb = m0 >> 11;

  // ---- Q,K epilogues: Tb row-major [128][68]; chunks (gl 0..3) x (kl 0..3) ----
#pragma unroll
  for (int z = 0; z < 2; ++z) {
    __syncthreads();
#pragma unroll
    for (int mi = 0; mi < 4; ++mi)
#pragma unroll
      for (int nj = 0; nj < 2; ++nj)
#pragma unroll
        for (int rr = 0; rr < 4; ++rr)
          Tb[(wm * 64 + mi * 16 + lane_q * 4 + rr) * 68 + wn * 32 + nj * 16 + lane_m] =
              f2bf(acc[z][mi][nj][rr]);
    __syncthreads();
    short* Odst = (z == 0) ? QP : KP;
    const int g0 = (m0 & 2047) >> 5, kst0 = n0 >> 4;
#pragma unroll
    for (int p = 0; p < 4; ++p) {
      const int c2 = p * 256 + tid;
      const int frag = c2 >> 6, ln2 = c2 & 63;
      const int gl = frag >> 2, kl = frag & 3;
      const short* src = Tb + (gl * 32 + (ln2 & 31)) * 68 + kl * 16 + ((ln2 >> 5) << 3);
      size_t dst = (size_t)bb * 1048576 + (size_t)((g0 + gl) * 32 + kst0 + kl) * 512 + ln2 * 8;
      *(bf16x8*)(Odst + dst) = *(const bf16x8*)src;
    }
  }
  // ---- V epilogue: Tb d-major [64][132]; chunks (ngl 0..1) x (kvl 0..7) ----
  {
    __syncthreads();
#pragma unroll
    for (int mi = 0; mi < 4; ++mi)
#pragma unroll
      for (int nj = 0; nj < 2; ++nj)
#pragma unroll
        for (int rr = 0; rr < 4; ++rr)
          Tb[(wn * 32 + nj * 16 + lane_m) * 132 + wm * 64 + mi * 16 + lane_q * 4 + rr] =
              f2bf(acc[2][mi][nj][rr]);
    __syncthreads();
    const int ng0 = n0 >> 5, kv0 = (m0 & 2047) >> 4;
#pragma unroll
    for (int p = 0; p < 4; ++p) {
      const int c2 = p * 256 + tid;
      const int frag = c2 >> 6, ln2 = c2 & 63;
      const int ngl = frag >> 3, kvl = frag & 7;
      const short* src = Tb + (ngl * 32 + (ln2 & 31)) * 132 + kvl * 16 + ((ln2 >> 5) << 3);
      size_t dst = (size_t)bb * 1048576 + (size_t)((ng0 + ngl) * 128 + kv0 + kvl) * 512 + ln2 * 8;
      *(bf16x8*)(VP + dst) = *(const bf16x8*)src;
    }
  }
}

// ---------------- kernel 2: flash attention, S^T/O^T 32x32, KVBLK=256, fixed roles ----------------
// (verified R15: ~75.5 us, VGPR 112, FETCH 24.6 MB, no spill) — byte-identical.

#define ISSUE8(R, a0_, a1_, B)                                               \
  asm volatile("global_load_dwordx4 %0, %8, %10\n\t"                         \
               "global_load_dwordx4 %1, %8, %10 offset:1024\n\t"             \
               "global_load_dwordx4 %2, %8, %10 offset:2048\n\t"             \
               "global_load_dwordx4 %3, %8, %10 offset:3072\n\t"             \
               "global_load_dwordx4 %4, %9, %10\n\t"                         \
               "global_load_dwordx4 %5, %9, %10 offset:1024\n\t"             \
               "global_load_dwordx4 %6, %9, %10 offset:2048\n\t"             \
               "global_load_dwordx4 %7, %9, %10 offset:3072\n\t"             \
               : "=&v"(R[0]), "=&v"(R[1]), "=&v"(R[2]), "=&v"(R[3]),         \
                 "=&v"(R[4]), "=&v"(R[5]), "=&v"(R[6]), "=&v"(R[7])          \
               : "v"(a0_), "v"(a1_), "s"(B))

#define WAIT8(R, N)                                                          \
  asm volatile("s_waitcnt vmcnt(" #N ")"                                     \
               : "+v"(R[0]), "+v"(R[1]), "+v"(R[2]), "+v"(R[3]),             \
                 "+v"(R[4]), "+v"(R[5]), "+v"(R[6]), "+v"(R[7]))

#define MFMA32(A, B, C) __builtin_amdgcn_mfma_f32_32x32x16_bf16(A, B, C, 0, 0, 0)

#define ISSUE_KQ(X, kt_, qq)                                                 \
  { const unsigned a0 = kb0 + (unsigned)(((kt_) & 7) * 262144) + (qq) * 8192u; \
    ISSUE8(X, a0, a0 + 4096u, Kp); }

#define ISSUE_VQ(X, kt_, bb_)                                                \
  { const unsigned a0 = vb0 + (unsigned)((kt_) * 16384) + (bb_) * 4096u;     \
    ISSUE8(X, a0, a0 + 131072u, VTp); }

#define S_PHASE(X, ph)                                                       \
  WAIT8(X, 8);                                                               \
  __builtin_amdgcn_s_setprio(1);                                             \
  _Pragma("unroll")                                                          \
  for (int c = 0; c < 8; ++c) {                                              \
    const int kst = (ph) * 8 + c;                                            \
    bf16x8 q0 = *(bf16x8*)(qf + kst * 512 + ln * 8);                         \
    bf16x8 q1 = *(bf16x8*)(qf + (32 + kst) * 512 + ln * 8);                  \
    s0 = MFMA32(X[c], q0, s0);                                               \
    s1 = MFMA32(X[c], q1, s1);                                               \
  }                                                                          \
  __builtin_amdgcn_s_setprio(0);

#define PF_RD(qh_, kv_)                                                      \
  (*(bf16x8*)(pfb + (qh_) * 8192 + q32 * 256 + ((((kv_) * 16) + hq8) ^ sw3)))

#define PV_PHASE(X, bb_)                                                     \
  WAIT8(X, 8);                                                               \
  __builtin_amdgcn_s_setprio(1);                                             \
  _Pragma("unroll")                                                          \
  for (int c = 0; c < 4; ++c) {                                              \
    const int kv = (bb_) * 4 + c;                                            \
    bf16x8 p0 = PF_RD(0, kv);                                                \
    bf16x8 p1 = PF_RD(1, kv);                                                \
    O00 = MFMA32(X[c], p0, O00);                                             \
    O01 = MFMA32(X[c], p1, O01);                                             \
    O10 = MFMA32(X[4 + c], p0, O10);                                         \
    O11 = MFMA32(X[4 + c], p1, O11);                                         \
  }                                                                          \
  __builtin_amdgcn_s_setprio(0);

__global__ __launch_bounds__(512, 2) void flash_kernel(const short* __restrict__ Q,
                                                       const short* __restrict__ K,
                                                       const short* __restrict__ VT,
                                                       float* __restrict__ out) {
  __shared__ __align__(16) short qf[32768];  // Q chunks [qb2][kst32] = 64 KB
  __shared__ __align__(16) short pf[32768];  // P^T [qh2][q32][k256], dbuf 2 x 32 KB
  __shared__ float l_red[8][64];
  __shared__ float lsum[64];

  const int tid = threadIdx.x, w = tid >> 6, ln = tid & 63;
  const int q32 = ln & 31, hq = ln >> 5;
  const int hq8 = hq * 8, hq4 = hq * 4;
  const int sw3 = (q32 & 7) << 3;
  const int b = blockIdx.x & 7, qt = blockIdx.x >> 3;
  const int m0 = qt * 64;
  const short* Qp = Q + (size_t)b * 1048576;
  const short* Kp = K + (size_t)b * 1048576;
  const short* VTp = VT + (size_t)b * 1048576;
  const float sc2 = 0.044194173824159216f * 1.4426950408889634f;  // 1/sqrt(512)*log2(e)

  // stage Q (64 chunks, straight copy; region = qb*32 + kst = chunk - qt*64)
#pragma unroll
  for (int r = 0; r < 8; ++r) {
    const int reg = w * 8 + r;
    *(bf16x8*)(qf + reg * 512 + ln * 8) =
        *(const bf16x8*)(Qp + (size_t)(qt * 64 + reg) * 512 + ln * 8);
  }

  f32x16 zz = {};
  f32x16 O00 = zz, O01 = zz, O10 = zz, O11 = zz;
  float lp0 = 0.f, lp1 = 0.f;

  const unsigned kb0 = (unsigned)(w * 32768 + ln * 16);
  const unsigned vb0 = (unsigned)(w * 262144 + ln * 16);

  __syncthreads();  // qf ready; vmcnt clean

  bf16x8 kX[8], kY[8], vA[8], vB[8];
  ISSUE_KQ(kX, 0, 0);
  ISSUE_KQ(kY, 0, 1);  // out = 16

#pragma unroll 1
  for (int kt = 0; kt < 8; ++kt) {
    f32x16 s0 = zz, s1 = zz;
    short* pfb = pf + (kt & 1) * 16384;

    S_PHASE(kX, 0); ISSUE_KQ(kX, kt, 2);
    S_PHASE(kY, 1); ISSUE_KQ(kY, kt, 3);
    S_PHASE(kX, 2); ISSUE_VQ(vA, kt, 0);
    S_PHASE(kY, 3); ISSUE_VQ(vB, kt, 1);

    // ---- inline softmax: p = 2^(s*sc2 - 12); write P^T b64 groups (swizzled); accumulate l ----
#pragma unroll
    for (int g2 = 0; g2 < 4; ++g2) {
      float a0 = exp2_raw(s0[g2 * 4 + 0] * sc2 - 12.0f);
      float a1 = exp2_raw(s0[g2 * 4 + 1] * sc2 - 12.0f);
      float a2 = exp2_raw(s0[g2 * 4 + 2] * sc2 - 12.0f);
      float a3 = exp2_raw(s0[g2 * 4 + 3] * sc2 - 12.0f);
      lp0 += (a0 + a1) + (a2 + a3);
      short4v v0c = {f2bf(a0), f2bf(a1), f2bf(a2), f2bf(a3)};
      *(short4v*)(pfb + q32 * 256 + (((w * 32 + g2 * 8) + hq4) ^ sw3)) = v0c;
      float c0 = exp2_raw(s1[g2 * 4 + 0] * sc2 - 12.0f);
      float c1 = exp2_raw(s1[g2 * 4 + 1] * sc2 - 12.0f);
      float c2 = exp2_raw(s1[g2 * 4 + 2] * sc2 - 12.0f);
      float c3 = exp2_raw(s1[g2 * 4 + 3] * sc2 - 12.0f);
      lp1 += (c0 + c1) + (c2 + c3);
      short4v v1c = {f2bf(c0), f2bf(c1), f2bf(c2), f2bf(c3)};
      *(short4v*)(pfb + 8192 + q32 * 256 + (((w * 32 + g2 * 8) + hq4) ^ sw3)) = v1c;
    }
    // RAW barrier: drain LDS only; V0,V1 (16 loads) stay in flight across it
    asm volatile("s_waitcnt lgkmcnt(0)" ::: "memory");
    __builtin_amdgcn_s_barrier();
    asm volatile("" ::: "memory");

    PV_PHASE(vA, 0); ISSUE_VQ(vA, kt, 2);
    PV_PHASE(vB, 1); ISSUE_VQ(vB, kt, 3);
    PV_PHASE(vA, 2); ISSUE_KQ(kX, kt + 1, 0);
    PV_PHASE(vB, 3); ISSUE_KQ(kY, kt + 1, 1);
  }
  // drain dangling wrapped-tile prefetches (register-tied)
  WAIT8(kX, 8);
  WAIT8(kY, 0);

  // ---- l: fold hq halves, publish per-wave partials, sum 8 waves ----
  lp0 += __shfl_xor(lp0, 32);
  lp1 += __shfl_xor(lp1, 32);
  if (ln < 32) {
    l_red[w][q32] = lp0;
    l_red[w][32 + q32] = lp1;
  }
  __syncthreads();
  if (tid < 64) {
    float s = 0.f;
#pragma unroll
    for (int ww = 0; ww < 8; ++ww) s += l_red[ww][tid];
    lsum[tid] = s;
  }
  __syncthreads();

  // ---- epilogue: O^T regs -> out[q][d], f32x4 packed stores (d-quads) ----
  const float li0 = 1.f / lsum[q32];
  const float li1 = 1.f / lsum[32 + q32];
#pragma unroll
  for (int g2 = 0; g2 < 4; ++g2) {
    const int dq = g2 * 8 + hq4;  // d-local base within ng: crow = i + 8*g2 + 4*hq
    const size_t r0 = ((size_t)b * 2048 + m0 + q32) * 512 + w * 64;
    const size_t r1 = ((size_t)b * 2048 + m0 + 32 + q32) * 512 + w * 64;
    f32x4 o;
    o[0] = O00[g2 * 4 + 0] * li0; o[1] = O00[g2 * 4 + 1] * li0;
    o[2] = O00[g2 * 4 + 2] * li0; o[3] = O00[g2 * 4 + 3] * li0;
    *(f32x4*)(out + r0 + dq) = o;
    o[0] = O10[g2 * 4 + 0] * li0; o[1] = O10[g2 * 4 + 1] * li0;
    o[2] = O10[g2 * 4 + 2] * li0; o[3] = O10[g2 * 4 + 3] * li0;
    *(f32x4*)(out + r0 + 32 + dq) = o;
    o[0] = O01[g2 * 4 + 0] * li1; o[1] = O01[g2 * 4 + 1] * li1;
    o[2] = O01[g2 * 4 + 2] * li1; o[3] = O01[g2 * 4 + 3] * li1;
    *(f32x4*)(out + r1 + dq) = o;
    o[0] = O11[g2 * 4 + 0] * li1; o[1] = O11[g2 * 4 + 1] * li1;
    o[2] = O11[g2 * 4 + 2] * li1; o[3] = O11[g2 * 4 + 3] * li1;
    *(f32x4*)(out + r1 + 32 + dq) = o;
  }
}

extern "C" void kernel_launch(void* const* d_in, const int* in_sizes, int n_in,
                              void* d_out, int out_size, void* d_ws, size_t ws_size,
                              hipStream_t stream) {
  const float* x  = (const float*)d_in[0];
  const float* Wq = (const float*)d_in[1];
  const float* Wk = (const float*)d_in[2];
  const float* Wv = (const float*)d_in[3];
  float* out = (float*)d_out;
  char* ws = (char*)d_ws;
  short* WT = (short*)ws;
  short* QP = (short*)(ws + 1572864);
  short* KP = (short*)(ws + 1572864 + 16777216);
  short* VP = (short*)(ws + 1572864 + 2 * 16777216);
  short* xb = (short*)(ws + 1572864 + 3 * 16777216);

  prep_kernel<<<dim3(384 + 4096), dim3(256), 0, stream>>>(x, Wq, Wk, Wv, WT, xb);
  proj_kernel<<<dim3(128, 8), dim3(256), 0, stream>>>(xb, WT, QP, KP, VP);
  flash_kernel<<<dim3(256), dim3(512), 0, stream>>>(QP, KP, VP, out);
}

// Round 12
// 199.079 us; speedup vs baseline: 1.2723x; 1.0225x over previous
//
#include <hip/hip_runtime.h>

// AttentionBlock: B=8, S=2048, D=512, fp32 in/out, bf16 MFMA internally.
// R19 = R18 (total 203.5 verified; flash 72, proj <72) with proj tile DOUBLED:
//   128x128 x 3z per block, 512 threads / 8 waves (per-wave shape unchanged:
//   64r x 32c x 3z, acc[3][4][2] = 96 regs). Grid (128,4) = 512 blocks = 2/CU.
//   A-panel L2 re-reads halve (4 n-blocks vs 8); staging 4 calls/wave (1A+3B);
//   barriers per output element halve. Sync skeleton = R18's verified
//   [stage k+1][vmcnt(4) lgkmcnt(0)][barrier][ds_read+MFMA][barrier].
// flash: S^T/O^T 32x32, 4 fixed-role 8-frag asm arrays, 1 barrier/iter, vmcnt(8),
//   setprio around MFMA, raw v_exp_f32 softmax. (R15, byte-identical.)
// Packed 32x32 chunk layouts (1KB contiguous wave-loads), produced by proj epilogue:
//   Q32/K32 chunk(g,kst): row = g*32+(l&31), d = kst*16+(l>>5)*8+j, idx = g*32+kst
//   V32     chunk(ng,kv): dim = ng*32+(l&31), key = kv*16+(l>>5)*8+j, idx = ng*128+kv
// ws: WT bf16[3][512][512] | QP 16MB | KP 16MB | VP 16MB | xb 16MB

typedef __attribute__((ext_vector_type(8))) short bf16x8;
typedef __attribute__((ext_vector_type(4))) short short4v;
typedef __attribute__((ext_vector_type(4))) float f32x4;
typedef __attribute__((ext_vector_type(16))) float f32x16;

__device__ __forceinline__ short f2bf(float f) {
  union { float f; unsigned u; } v; v.f = f;
  unsigned r = v.u + 0x7fffu + ((v.u >> 16) & 1u);
  return (short)(r >> 16);
}

__device__ __forceinline__ float exp2_raw(float x) {
  float r;
  asm("v_exp_f32 %0, %1" : "=v"(r) : "v"(x));
  return r;
}

__device__ __forceinline__ void async_cp16(const void* g, void* l) {
  __builtin_amdgcn_global_load_lds(
      (const __attribute__((address_space(1))) unsigned int*)g,
      (__attribute__((address_space(3))) unsigned int*)l, 16, 0, 0);
}

// ---------------- kernel 0: prep = W transpose+cvt  AND  x -> bf16 ----------------
__global__ __launch_bounds__(256) void prep_kernel(const float* __restrict__ x,
                                                   const float* __restrict__ Wq,
                                                   const float* __restrict__ Wk,
                                                   const float* __restrict__ Wv,
                                                   short* __restrict__ WT,
                                                   short* __restrict__ xb) {
  if (blockIdx.x < 384) {
    int g = blockIdx.x * 256 + threadIdx.x;  // 3*512*64
    int w = g >> 15;
    int rem = g & 32767;
    int n = rem & 511;
    int k0 = (rem >> 9) << 3;
    const float* W = (w == 0) ? Wq : ((w == 1) ? Wk : Wv);
    bf16x8 o;
#pragma unroll
    for (int j = 0; j < 8; ++j) o[j] = f2bf(W[(k0 + j) * 512 + n]);
    *(bf16x8*)(WT + w * 262144 + n * 512 + k0) = o;
  } else {
    size_t g = (size_t)(blockIdx.x - 384) * 256 + threadIdx.x;
    size_t off = g * 8;
    f32x4 lo = *(const f32x4*)(x + off);
    f32x4 hi = *(const f32x4*)(x + off + 4);
    bf16x8 o;
    o[0] = f2bf(lo[0]); o[1] = f2bf(lo[1]); o[2] = f2bf(lo[2]); o[3] = f2bf(lo[3]);
    o[4] = f2bf(hi[0]); o[5] = f2bf(hi[1]); o[6] = f2bf(hi[2]); o[7] = f2bf(hi[3]);
    *(bf16x8*)(xb + off) = o;
  }
}

// ---------------- kernel 1: Z-FUSED proj GEMM, 128x128 tile, dbuf + counted vmcnt ----------------
// grid (128, 4): m0 = bx*128, n0 = by*128. 8 waves: wm = wv&1 (64-row half),
// wn = wv>>1 (32-col group, 0..3). Per BK=32 step, per wave: stage 4 async_cp16
// (1 A region mt=wv + 3 B regions nt=wv per z), then 10 ds_read_b128 + 24 MFMA.
__global__ __launch_bounds__(512, 2) void proj_kernel(const short* __restrict__ xb,
                                                      const short* __restrict__ WT,
                                                      short* __restrict__ QP,
                                                      short* __restrict__ KP,
                                                      short* __restrict__ VP) {
  __shared__ __align__(16) short smem[32768];  // dbuf 2 x (Af 4096 + Bf 12288); Tb (17408) aliases
  short* Tb = smem;

  const int tid = threadIdx.x, wv = tid >> 6, ln = tid & 63;
  const int lane_m = ln & 15, lane_q = ln >> 4;
  const int m0 = blockIdx.x * 128, n0 = blockIdx.y * 128;
  const int wm = wv & 1, wn = wv >> 1;

  f32x4 zero4 = {0.f, 0.f, 0.f, 0.f};
  f32x4 acc[3][4][2];
#pragma unroll
  for (int z = 0; z < 3; ++z)
#pragma unroll
    for (int i = 0; i < 4; ++i)
#pragma unroll
      for (int j = 0; j < 2; ++j) acc[z][i][j] = zero4;

#define PROJ_STAGE(kk_, buf_)                                                          \
  {                                                                                    \
    const int k0s = (kk_) * 32;                                                        \
    short* Afs = smem + (buf_) * 16384;                                                \
    short* Bfs = Afs + 4096;                                                           \
    async_cp16(xb + (size_t)(m0 + wv * 16 + lane_m) * 512 + k0s + lane_q * 8,          \
               Afs + wv * 512);                                                        \
    _Pragma("unroll")                                                                  \
    for (int z = 0; z < 3; ++z)                                                        \
      async_cp16(WT + z * 262144 + (size_t)(n0 + wv * 16 + lane_m) * 512 + k0s +       \
                     lane_q * 8,                                                       \
                 Bfs + z * 4096 + wv * 512);                                           \
  }

  PROJ_STAGE(0, 0);  // 4 loads in flight per wave

#pragma unroll 1
  for (int kk = 0; kk < 16; ++kk) {
    if (kk < 15) {
      PROJ_STAGE(kk + 1, (kk + 1) & 1);  // outstanding = 8 per wave
      asm volatile("s_waitcnt vmcnt(4) lgkmcnt(0)" ::: "memory");  // stage kk landed
    } else {
      asm volatile("s_waitcnt vmcnt(0) lgkmcnt(0)" ::: "memory");
    }
    __builtin_amdgcn_s_barrier();
    asm volatile("" ::: "memory");

    short* Af = smem + (kk & 1) * 16384;
    short* Bf = Af + 4096;
    bf16x8 a[4];
#pragma unroll
    for (int mi = 0; mi < 4; ++mi) a[mi] = *(bf16x8*)(Af + ((wm * 4 + mi) * 64 + ln) * 8);
#pragma unroll
    for (int z = 0; z < 3; ++z) {
      bf16x8 b0 = *(bf16x8*)(Bf + z * 4096 + (wn * 2 + 0) * 512 + ln * 8);
      bf16x8 b1 = *(bf16x8*)(Bf + z * 4096 + (wn * 2 + 1) * 512 + ln * 8);
#pragma unroll
      for (int mi = 0; mi < 4; ++mi) {
        acc[z][mi][0] = __builtin_amdgcn_mfma_f32_16x16x32_bf16(a[mi], b0, acc[z][mi][0], 0, 0, 0);
        acc[z][mi][1] = __builtin_amdgcn_mfma_f32_16x16x32_bf16(a[mi], b1, acc[z][mi][1], 0, 0, 0);
      }
    }
    asm volatile("" ::: "memory");
    __builtin_amdgcn_s_barrier();  // all waves done reading buf kk&1 before its reuse
  }

  const int bb = m0 >> 11;

  // ---- Q,K epilogues: Tb row-major [128][136]; chunks (gl 0..3) x (kl 0..7) ----
#pragma unroll
  for (int z = 0; z < 2; ++z) {
    __syncthreads();
#pragma unroll
    for (int mi = 0; mi < 4; ++mi)
#pragma unroll
      for (int nj = 0; nj < 2; ++nj)
#pragma unroll
        for (int rr = 0; rr < 4; ++rr)
          Tb[(wm * 64 + mi * 16 + lane_q * 4 + rr) * 136 + wn * 32 + nj * 16 + lane_m] =
              f2bf(acc[z][mi][nj][rr]);
    __syncthreads();
    short* Odst = (z == 0) ? QP : KP;
    const int g0 = (m0 & 2047) >> 5, kst0 = n0 >> 4;
#pragma unroll
    for (int p = 0; p < 4; ++p) {
      const int c2 = p * 512 + tid;
      const int frag = c2 >> 6, ln2 = c2 & 63;
      const int gl = frag >> 3, kl = frag & 7;
      const short* src = Tb + (gl * 32 + (ln2 & 31)) * 136 + kl * 16 + ((ln2 >> 5) << 3);
      size_t dst = (size_t)bb * 1048576 + (size_t)((g0 + gl) * 32 + kst0 + kl) * 512 + ln2 * 8;
      *(bf16x8*)(Odst + dst) = *(const bf16x8*)src;
    }
  }
  // ---- V epilogue: Tb d-major [128][136]; chunks (ngl 0..3) x (kvl 0..7) ----
  {
    __syncthreads();
#pragma unroll
    for (int mi = 0; mi < 4; ++mi)
#pragma unroll
      for (int nj = 0; nj < 2; ++nj)
#pragma unroll
        for (int rr = 0; rr < 4; ++rr)
          Tb[(wn * 32 + nj * 16 + lane_m) * 136 + wm * 64 + mi * 16 + lane_q * 4 + rr] =
              f2bf(acc[2][mi][nj][rr]);
    __syncthreads();
    const int ng0 = n0 >> 5, kv0 = (m0 & 2047) >> 4;
#pragma unroll
    for (int p = 0; p < 4; ++p) {
      const int c2 = p * 512 + tid;
      const int frag = c2 >> 6, ln2 = c2 & 63;
      const int ngl = frag >> 3, kvl = frag & 7;
      const short* src = Tb + (ngl * 32 + (ln2 & 31)) * 136 + kvl * 16 + ((ln2 >> 5) << 3);
      size_t dst = (size_t)bb * 1048576 + (size_t)((ng0 + ngl) * 128 + kv0 + kvl) * 512 + ln2 * 8;
      *(bf16x8*)(VP + dst) = *(const bf16x8*)src;
    }
  }
}

// ---------------- kernel 2: flash attention, S^T/O^T 32x32, KVBLK=256, fixed roles ----------------
// (verified R15/R18: ~72-76 us, VGPR 112, FETCH 24.65 MB, no spill) — byte-identical.

#define ISSUE8(R, a0_, a1_, B)                                               \
  asm volatile("global_load_dwordx4 %0, %8, %10\n\t"                         \
               "global_load_dwordx4 %1, %8, %10 offset:1024\n\t"             \
               "global_load_dwordx4 %2, %8, %10 offset:2048\n\t"             \
               "global_load_dwordx4 %3, %8, %10 offset:3072\n\t"             \
               "global_load_dwordx4 %4, %9, %10\n\t"                         \
               "global_load_dwordx4 %5, %9, %10 offset:1024\n\t"             \
               "global_load_dwordx4 %6, %9, %10 offset:2048\n\t"             \
               "global_load_dwordx4 %7, %9, %10 offset:3072\n\t"             \
               : "=&v"(R[0]), "=&v"(R[1]), "=&v"(R[2]), "=&v"(R[3]),         \
                 "=&v"(R[4]), "=&v"(R[5]), "=&v"(R[6]), "=&v"(R[7])          \
               : "v"(a0_), "v"(a1_), "s"(B))

#define WAIT8(R, N)                                                          \
  asm volatile("s_waitcnt vmcnt(" #N ")"                                     \
               : "+v"(R[0]), "+v"(R[1]), "+v"(R[2]), "+v"(R[3]),             \
                 "+v"(R[4]), "+v"(R[5]), "+v"(R[6]), "+v"(R[7]))

#define MFMA32(A, B, C) __builtin_amdgcn_mfma_f32_32x32x16_bf16(A, B, C, 0, 0, 0)

#define ISSUE_KQ(X, kt_, qq)                                                 \
  { const unsigned a0 = kb0 + (unsigned)(((kt_) & 7) * 262144) + (qq) * 8192u; \
    ISSUE8(X, a0, a0 + 4096u, Kp); }

#define ISSUE_VQ(X, kt_, bb_)                                                \
  { const unsigned a0 = vb0 + (unsigned)((kt_) * 16384) + (bb_) * 4096u;     \
    ISSUE8(X, a0, a0 + 131072u, VTp); }

#define S_PHASE(X, ph)                                                       \
  WAIT8(X, 8);                                                               \
  __builtin_amdgcn_s_setprio(1);                                             \
  _Pragma("unroll")                                                          \
  for (int c = 0; c < 8; ++c) {                                              \
    const int kst = (ph) * 8 + c;                                            \
    bf16x8 q0 = *(bf16x8*)(qf + kst * 512 + ln * 8);                         \
    bf16x8 q1 = *(bf16x8*)(qf + (32 + kst) * 512 + ln * 8);                  \
    s0 = MFMA32(X[c], q0, s0);                                               \
    s1 = MFMA32(X[c], q1, s1);                                               \
  }                                                                          \
  __builtin_amdgcn_s_setprio(0);

#define PF_RD(qh_, kv_)                                                      \
  (*(bf16x8*)(pfb + (qh_) * 8192 + q32 * 256 + ((((kv_) * 16) + hq8) ^ sw3)))

#define PV_PHASE(X, bb_)                                                     \
  WAIT8(X, 8);                                                               \
  __builtin_amdgcn_s_setprio(1);                                             \
  _Pragma("unroll")                                                          \
  for (int c = 0; c < 4; ++c) {                                              \
    const int kv = (bb_) * 4 + c;                                            \
    bf16x8 p0 = PF_RD(0, kv);                                                \
    bf16x8 p1 = PF_RD(1, kv);                                                \
    O00 = MFMA32(X[c], p0, O00);                                             \
    O01 = MFMA32(X[c], p1, O01);                                             \
    O10 = MFMA32(X[4 + c], p0, O10);                                         \
    O11 = MFMA32(X[4 + c], p1, O11);                                         \
  }                                                                          \
  __builtin_amdgcn_s_setprio(0);

__global__ __launch_bounds__(512, 2) void flash_kernel(const short* __restrict__ Q,
                                                       const short* __restrict__ K,
                                                       const short* __restrict__ VT,
                                                       float* __restrict__ out) {
  __shared__ __align__(16) short qf[32768];  // Q chunks [qb2][kst32] = 64 KB
  __shared__ __align__(16) short pf[32768];  // P^T [qh2][q32][k256], dbuf 2 x 32 KB
  __shared__ float l_red[8][64];
  __shared__ float lsum[64];

  const int tid = threadIdx.x, w = tid >> 6, ln = tid & 63;
  const int q32 = ln & 31, hq = ln >> 5;
  const int hq8 = hq * 8, hq4 = hq * 4;
  const int sw3 = (q32 & 7) << 3;
  const int b = blockIdx.x & 7, qt = blockIdx.x >> 3;
  const int m0 = qt * 64;
  const short* Qp = Q + (size_t)b * 1048576;
  const short* Kp = K + (size_t)b * 1048576;
  const short* VTp = VT + (size_t)b * 1048576;
  const float sc2 = 0.044194173824159216f * 1.4426950408889634f;  // 1/sqrt(512)*log2(e)

  // stage Q (64 chunks, straight copy; region = qb*32 + kst = chunk - qt*64)
#pragma unroll
  for (int r = 0; r < 8; ++r) {
    const int reg = w * 8 + r;
    *(bf16x8*)(qf + reg * 512 + ln * 8) =
        *(const bf16x8*)(Qp + (size_t)(qt * 64 + reg) * 512 + ln * 8);
  }

  f32x16 zz = {};
  f32x16 O00 = zz, O01 = zz, O10 = zz, O11 = zz;
  float lp0 = 0.f, lp1 = 0.f;

  const unsigned kb0 = (unsigned)(w * 32768 + ln * 16);
  const unsigned vb0 = (unsigned)(w * 262144 + ln * 16);

  __syncthreads();  // qf ready; vmcnt clean

  bf16x8 kX[8], kY[8], vA[8], vB[8];
  ISSUE_KQ(kX, 0, 0);
  ISSUE_KQ(kY, 0, 1);  // out = 16

#pragma unroll 1
  for (int kt = 0; kt < 8; ++kt) {
    f32x16 s0 = zz, s1 = zz;
    short* pfb = pf + (kt & 1) * 16384;

    S_PHASE(kX, 0); ISSUE_KQ(kX, kt, 2);
    S_PHASE(kY, 1); ISSUE_KQ(kY, kt, 3);
    S_PHASE(kX, 2); ISSUE_VQ(vA, kt, 0);
    S_PHASE(kY, 3); ISSUE_VQ(vB, kt, 1);

    // ---- inline softmax: p = 2^(s*sc2 - 12); write P^T b64 groups (swizzled); accumulate l ----
#pragma unroll
    for (int g2 = 0; g2 < 4; ++g2) {
      float a0 = exp2_raw(s0[g2 * 4 + 0] * sc2 - 12.0f);
      float a1 = exp2_raw(s0[g2 * 4 + 1] * sc2 - 12.0f);
      float a2 = exp2_raw(s0[g2 * 4 + 2] * sc2 - 12.0f);
      float a3 = exp2_raw(s0[g2 * 4 + 3] * sc2 - 12.0f);
      lp0 += (a0 + a1) + (a2 + a3);
      short4v v0c = {f2bf(a0), f2bf(a1), f2bf(a2), f2bf(a3)};
      *(short4v*)(pfb + q32 * 256 + (((w * 32 + g2 * 8) + hq4) ^ sw3)) = v0c;
      float c0 = exp2_raw(s1[g2 * 4 + 0] * sc2 - 12.0f);
      float c1 = exp2_raw(s1[g2 * 4 + 1] * sc2 - 12.0f);
      float c2 = exp2_raw(s1[g2 * 4 + 2] * sc2 - 12.0f);
      float c3 = exp2_raw(s1[g2 * 4 + 3] * sc2 - 12.0f);
      lp1 += (c0 + c1) + (c2 + c3);
      short4v v1c = {f2bf(c0), f2bf(c1), f2bf(c2), f2bf(c3)};
      *(short4v*)(pfb + 8192 + q32 * 256 + (((w * 32 + g2 * 8) + hq4) ^ sw3)) = v1c;
    }
    // RAW barrier: drain LDS only; V0,V1 (16 loads) stay in flight across it
    asm volatile("s_waitcnt lgkmcnt(0)" ::: "memory");
    __builtin_amdgcn_s_barrier();
    asm volatile("" ::: "memory");

    PV_PHASE(vA, 0); ISSUE_VQ(vA, kt, 2);
    PV_PHASE(vB, 1); ISSUE_VQ(vB, kt, 3);
    PV_PHASE(vA, 2); ISSUE_KQ(kX, kt + 1, 0);
    PV_PHASE(vB, 3); ISSUE_KQ(kY, kt + 1, 1);
  }
  // drain dangling wrapped-tile prefetches (register-tied)
  WAIT8(kX, 8);
  WAIT8(kY, 0);

  // ---- l: fold hq halves, publish per-wave partials, sum 8 waves ----
  lp0 += __shfl_xor(lp0, 32);
  lp1 += __shfl_xor(lp1, 32);
  if (ln < 32) {
    l_red[w][q32] = lp0;
    l_red[w][32 + q32] = lp1;
  }
  __syncthreads();
  if (tid < 64) {
    float s = 0.f;
#pragma unroll
    for (int ww = 0; ww < 8; ++ww) s += l_red[ww][tid];
    lsum[tid] = s;
  }
  __syncthreads();

  // ---- epilogue: O^T regs -> out[q][d], f32x4 packed stores (d-quads) ----
  const float li0 = 1.f / lsum[q32];
  const float li1 = 1.f / lsum[32 + q32];
#pragma unroll
  for (int g2 = 0; g2 < 4; ++g2) {
    const int dq = g2 * 8 + hq4;  // d-local base within ng: crow = i + 8*g2 + 4*hq
    const size_t r0 = ((size_t)b * 2048 + m0 + q32) * 512 + w * 64;
    const size_t r1 = ((size_t)b * 2048 + m0 + 32 + q32) * 512 + w * 64;
    f32x4 o;
    o[0] = O00[g2 * 4 + 0] * li0; o[1] = O00[g2 * 4 + 1] * li0;
    o[2] = O00[g2 * 4 + 2] * li0; o[3] = O00[g2 * 4 + 3] * li0;
    *(f32x4*)(out + r0 + dq) = o;
    o[0] = O10[g2 * 4 + 0] * li0; o[1] = O10[g2 * 4 + 1] * li0;
    o[2] = O10[g2 * 4 + 2] * li0; o[3] = O10[g2 * 4 + 3] * li0;
    *(f32x4*)(out + r0 + 32 + dq) = o;
    o[0] = O01[g2 * 4 + 0] * li1; o[1] = O01[g2 * 4 + 1] * li1;
    o[2] = O01[g2 * 4 + 2] * li1; o[3] = O01[g2 * 4 + 3] * li1;
    *(f32x4*)(out + r1 + dq) = o;
    o[0] = O11[g2 * 4 + 0] * li1; o[1] = O11[g2 * 4 + 1] * li1;
    o[2] = O11[g2 * 4 + 2] * li1; o[3] = O11[g2 * 4 + 3] * li1;
    *(f32x4*)(out + r1 + 32 + dq) = o;
  }
}

extern "C" void kernel_launch(void* const* d_in, const int* in_sizes, int n_in,
                              void* d_out, int out_size, void* d_ws, size_t ws_size,
                              hipStream_t stream) {
  const float* x  = (const float*)d_in[0];
  const float* Wq = (const float*)d_in[1];
  const float* Wk = (const float*)d_in[2];
  const float* Wv = (const float*)d_in[3];
  float* out = (float*)d_out;
  char* ws = (char*)d_ws;
  short* WT = (short*)ws;
  short* QP = (short*)(ws + 1572864);
  short* KP = (short*)(ws + 1572864 + 16777216);
  short* VP = (short*)(ws + 1572864 + 2 * 16777216);
  short* xb = (short*)(ws + 1572864 + 3 * 16777216);

  prep_kernel<<<dim3(384 + 4096), dim3(256), 0, stream>>>(x, Wq, Wk, Wv, WT, xb);
  proj_kernel<<<dim3(128, 4), dim3(512), 0, stream>>>(xb, WT, QP, KP, VP);
  flash_kernel<<<dim3(256), dim3(512), 0, stream>>>(QP, KP, VP, out);
}